// Round 1
// baseline (148.281 us; speedup 1.0000x reference)
//
#include <hip/hip_runtime.h>
#include <stdint.h>

#define BHn 64
#define Mn 1024
#define SPANn 1024
#define DHn 64
#define NKEY (Mn + SPANn)
#define BQ 64
#define BK 64
#define NITER 17                       // covers l in [0,1023] for 64 q rows
#define RSQRT_D 0.044194173824159216f  // 1/sqrt(512)

typedef short short8 __attribute__((ext_vector_type(8)));
typedef float f32x4 __attribute__((ext_vector_type(4)));

#define KSTR 72    // padded LDS stride (bf16 elems) for K / Vt / P
#define PSTR 136   // padded stride for pos circular buffer (128 entries)

__device__ inline short f2bf(float x) {
    union { float f; unsigned int u; } v; v.f = x;
    unsigned int u = v.u;
    unsigned int r = (u + 0x7FFFu + ((u >> 16) & 1u)) >> 16;
    return (short)r;
}
__device__ inline float bf2f(short s) {
    union { unsigned int u; float f; } v;
    v.u = ((unsigned int)(unsigned short)s) << 16;
    return v.f;
}

__global__ void pe_transpose_kernel(const float* __restrict__ pe,
                                    short* __restrict__ peT) {
    int idx = blockIdx.x * blockDim.x + threadIdx.x;  // 65536 total
    int l = idx >> 6, d = idx & 63;
    peT[l * DHn + d] = f2bf(pe[d * SPANn + l]);
}

__global__ __launch_bounds__(256, 3) void attn_kernel(
    const float* __restrict__ q, const float* __restrict__ key,
    const float* __restrict__ val, const short* __restrict__ peT,
    const float* __restrict__ cur, float* __restrict__ out) {
    __shared__ short K_lds[BK][KSTR];
    __shared__ short Vt_lds[DHn][KSTR];
    __shared__ short P_lds[BQ][KSTR];
    __shared__ short Pos_lds[BQ][PSTR];

    // XCD-friendly decode: g = mtile*64 + b  ->  g%8 == b%8 (same XCD per b)
    const int b = blockIdx.x & 63;
    const int m0 = (blockIdx.x >> 6) << 6;
    const int head = b & 7;
    const int tid = threadIdx.x;
    const int lane = tid & 63;
    const int w = tid >> 6;    // wave 0..3 (16 q-rows each)
    const int l15 = lane & 15;
    const int lh = lane >> 4;  // 0..3

    const float cv = cur[head];
    const float c_h = (cv * (float)SPANn - (float)(SPANn - 1)) * (1.0f / 32.0f) + 1.0f;

    // ---- Q A-fragments (pre-scaled by 1/sqrt(D_MODEL)), kept in regs ----
    // A layout: row = lane&15, k = 8*(lane>>4)+e ; kstep t covers d = 32t+k
    short8 qfrag[2];
    {
        const float* qrow = q + ((size_t)b * Mn + (m0 + 16 * w + l15)) * DHn;
#pragma unroll
        for (int t = 0; t < 2; ++t) {
            int d0 = 32 * t + 8 * lh;
#pragma unroll
            for (int e = 0; e < 8; ++e)
                qfrag[t][e] = f2bf(qrow[d0 + e] * RSQRT_D);
        }
    }

    f32x4 o_acc[4];
#pragma unroll
    for (int c = 0; c < 4; ++c) o_acc[c] = (f32x4){0.f, 0.f, 0.f, 0.f};
    float zsum[4] = {0.f, 0.f, 0.f, 0.f};
    float zmsum[4] = {0.f, 0.f, 0.f, 0.f};

    const int r_stage = tid >> 2;          // 0..63
    const int c_stage = (tid & 3) * 16;    // 0,16,32,48

#pragma unroll 1
    for (int t = 0; t < NITER; ++t) {
        const int n0 = m0 + 64 * t;
        const int D = 64 * t;

        __syncthreads();  // previous iteration done reading K/Vt

        // ---- stage K tile (bf16, padded) ----
        {
            const float* src = key + ((size_t)b * NKEY + (n0 + r_stage)) * DHn + c_stage;
            short8 a0, a1;
#pragma unroll
            for (int e = 0; e < 8; ++e) a0[e] = f2bf(src[e]);
#pragma unroll
            for (int e = 0; e < 8; ++e) a1[e] = f2bf(src[8 + e]);
            *(short8*)&K_lds[r_stage][c_stage] = a0;
            *(short8*)&K_lds[r_stage][c_stage + 8] = a1;
        }
        // ---- stage V tile transposed: Vt[d][j] = V[n0+j][d] ----
        {
            const float* src = val + ((size_t)b * NKEY + (n0 + r_stage)) * DHn + c_stage;
#pragma unroll
            for (int e = 0; e < 16; ++e)
                Vt_lds[c_stage + e][r_stage] = f2bf(src[e]);
        }
        // ---- pos chunk GEMM: Pos[i][l0+jl] = qs[i] . peT[l0+jl] ----
        if (t < 16) {
            const int l0 = 64 * t;
#pragma unroll
            for (int c = 0; c < 4; ++c) {
                int lcol = l0 + 16 * c + l15;
                short8 b0 = *(const short8*)&peT[(size_t)lcol * DHn + 8 * lh];
                short8 b1 = *(const short8*)&peT[(size_t)lcol * DHn + 32 + 8 * lh];
                f32x4 acc = (f32x4){0.f, 0.f, 0.f, 0.f};
                acc = __builtin_amdgcn_mfma_f32_16x16x32_bf16(qfrag[0], b0, acc, 0, 0, 0);
                acc = __builtin_amdgcn_mfma_f32_16x16x32_bf16(qfrag[1], b1, acc, 0, 0, 0);
                int ent = lcol & 127;
#pragma unroll
                for (int r = 0; r < 4; ++r) {
                    int i = 16 * w + 4 * lh + r;
                    Pos_lds[i][ent] = f2bf(acc[r]);
                }
            }
        }

        __syncthreads();  // K/Vt/Pos visible to all

        // ---- S = Q K^T, add pos, exp, mask, write P ----
#pragma unroll
        for (int c = 0; c < 4; ++c) {
            short8 k0 = *(const short8*)&K_lds[16 * c + l15][8 * lh];
            short8 k1 = *(const short8*)&K_lds[16 * c + l15][32 + 8 * lh];
            f32x4 acc = (f32x4){0.f, 0.f, 0.f, 0.f};
            acc = __builtin_amdgcn_mfma_f32_16x16x32_bf16(qfrag[0], k0, acc, 0, 0, 0);
            acc = __builtin_amdgcn_mfma_f32_16x16x32_bf16(qfrag[1], k1, acc, 0, 0, 0);
#pragma unroll
            for (int r = 0; r < 4; ++r) {
                int i = 16 * w + 4 * lh + r;
                int l = D + 16 * c + l15 - (16 * w + 4 * lh + r);
                bool valid = (l >= 0) && (l < SPANn);
                float pos = bf2f(Pos_lds[i][l & 127]);
                float s = acc[r] + pos;
                float p = __expf(s);
                p = valid ? p : 0.0f;
                float mk = fminf(fmaxf((float)l * (1.0f / 32.0f) + c_h, 0.0f), 1.0f);
                float pm = p * mk;
                zsum[r] += p;
                zmsum[r] += pm;
                P_lds[i][16 * c + l15] = f2bf(pm);
            }
        }

        __syncthreads();  // insurance: P writes visible before PV reads

        // ---- PV: O += P * V ----
#pragma unroll
        for (int c = 0; c < 4; ++c) {
            short8 p0 = *(const short8*)&P_lds[16 * w + l15][8 * lh];
            short8 p1 = *(const short8*)&P_lds[16 * w + l15][32 + 8 * lh];
            short8 v0 = *(const short8*)&Vt_lds[16 * c + l15][8 * lh];
            short8 v1 = *(const short8*)&Vt_lds[16 * c + l15][32 + 8 * lh];
            o_acc[c] = __builtin_amdgcn_mfma_f32_16x16x32_bf16(p0, v0, o_acc[c], 0, 0, 0);
            o_acc[c] = __builtin_amdgcn_mfma_f32_16x16x32_bf16(p1, v1, o_acc[c], 0, 0, 0);
        }
    }

    // ---- row sums across the 16 lanes holding each row's columns ----
#pragma unroll
    for (int r = 0; r < 4; ++r) {
#pragma unroll
        for (int off = 1; off < 16; off <<= 1) {
            zsum[r] += __shfl_xor(zsum[r], off, 64);
            zmsum[r] += __shfl_xor(zmsum[r], off, 64);
        }
    }

    // ---- epilogue: out = O / (zm + 1e-8 * z) ----
#pragma unroll
    for (int r = 0; r < 4; ++r) {
        float denom = 1.0f / (zmsum[r] + 1e-8f * zsum[r]);
        int i = 16 * w + 4 * lh + r;
        float* orow = out + ((size_t)b * Mn + (m0 + i)) * DHn;
#pragma unroll
        for (int c = 0; c < 4; ++c)
            orow[16 * c + l15] = o_acc[c][r] * denom;
    }
}

extern "C" void kernel_launch(void* const* d_in, const int* in_sizes, int n_in,
                              void* d_out, int out_size, void* d_ws, size_t ws_size,
                              hipStream_t stream) {
    (void)in_sizes; (void)n_in; (void)out_size; (void)ws_size;
    const float* q = (const float*)d_in[0];
    const float* key = (const float*)d_in[1];
    const float* val = (const float*)d_in[2];
    const float* pe = (const float*)d_in[3];
    const float* cur = (const float*)d_in[4];
    float* out = (float*)d_out;
    short* peT = (short*)d_ws;  // 1024*64 bf16 = 128 KB

    pe_transpose_kernel<<<256, 256, 0, stream>>>(pe, peT);
    attn_kernel<<<64 * (Mn / BQ), 256, 0, stream>>>(q, key, val, peT, cur, out);
}

// Round 2
// 98.954 us; speedup vs baseline: 1.4985x; 1.4985x over previous
//
#include <hip/hip_runtime.h>
#include <stdint.h>

#define BHn 64
#define Mn 1024
#define SPANn 1024
#define DHn 64
#define NKEY (Mn + SPANn)
#define NITER 17
#define RSQRT_D 0.044194173824159216f  // 1/sqrt(512)
#define POS_STR 132                    // shorts per Pos row (264B, odd dword count)

typedef short s16x8 __attribute__((ext_vector_type(8)));
typedef short s16x4 __attribute__((ext_vector_type(4)));
typedef float f32x4 __attribute__((ext_vector_type(4)));

__device__ __forceinline__ short f2bf(float x) {
    union { float f; unsigned int u; } v; v.f = x;
    unsigned int u = v.u;
    unsigned int r = (u + 0x7FFFu + ((u >> 16) & 1u)) >> 16;
    return (short)r;
}
__device__ __forceinline__ float bf2f(short s) {
    union { unsigned int u; float f; } v;
    v.u = ((unsigned int)(unsigned short)s) << 16;
    return v.f;
}

__device__ __forceinline__ void gload16(const void* g, void* l) {
    __builtin_amdgcn_global_load_lds(
        (const __attribute__((address_space(1))) void*)g,
        (__attribute__((address_space(3))) void*)l, 16, 0, 0);
}

// Stage a 64x64 bf16 tile (rows of 64 shorts) into linear LDS with the
// st-style XOR swizzle applied on the SOURCE column (read side XORs the same).
__device__ __forceinline__ void stage64x64(const short* srcbase, int src_stride,
                                           short* ldsbase, int tid) {
    const int scol = (((tid & 7) ^ ((tid >> 3) & 7)) << 3);  // shorts
    const int wofs = (tid >> 6) << 9;                        // w*512 shorts
#pragma unroll
    for (int qh = 0; qh < 2; ++qh) {
        const short* src = srcbase + (size_t)((qh << 5) + (tid >> 3)) * src_stride + scol;
        short* dst = ldsbase + (qh << 11) + wofs;  // wave-uniform base
        gload16(src, dst);
    }
}

// ---------------- prepass kernels ----------------
__global__ void k_convert_kernel(const float* __restrict__ K, short* __restrict__ Kb) {
    size_t idx = ((size_t)blockIdx.x * 256 + threadIdx.x) * 8;
    const float* p = K + idx;
    s16x8 o;
#pragma unroll
    for (int e = 0; e < 8; ++e) o[e] = f2bf(p[e]);
    *(s16x8*)(Kb + idx) = o;
}

__global__ void v_transpose_kernel(const float* __restrict__ V, short* __restrict__ Vt) {
    __shared__ float tile[64][65];
    int b = blockIdx.x >> 5;
    int n0 = (blockIdx.x & 31) << 6;
    int r = threadIdx.x >> 2;
    int c0 = (threadIdx.x & 3) << 4;
    const float* src = V + ((size_t)b * NKEY + n0 + r) * DHn + c0;
#pragma unroll
    for (int e = 0; e < 16; ++e) tile[r][c0 + e] = src[e];
    __syncthreads();
    short* dst = Vt + ((size_t)b * DHn + r) * NKEY + n0 + c0;
#pragma unroll
    for (int e = 0; e < 16; ++e) dst[e] = f2bf(tile[c0 + e][r]);
}

__global__ void pe_transpose_kernel(const float* __restrict__ pe, short* __restrict__ peT) {
    int idx = blockIdx.x * blockDim.x + threadIdx.x;  // 65536
    int l = idx >> 6, d = idx & 63;
    peT[l * DHn + d] = f2bf(pe[d * SPANn + l]);
}

// ---------------- main attention kernel (fast path) ----------------
__global__ __launch_bounds__(256, 2) void attn2_kernel(
    const float* __restrict__ q, const short* __restrict__ Kb,
    const short* __restrict__ Vt, const short* __restrict__ peT,
    const float* __restrict__ cur, float* __restrict__ out) {
    __shared__ short KA[2][4096];
    __shared__ short VA[2][4096];
    __shared__ short PE[2][4096];
    __shared__ short P[4096];
    __shared__ short Pos[64 * POS_STR];

    const int b = blockIdx.x & 63;          // g%8==b%8 -> per-b XCD locality
    const int m0 = (blockIdx.x >> 6) << 6;
    const int head = b & 7;
    const int tid = threadIdx.x;
    const int lane = tid & 63;
    const int w = tid >> 6;
    const int l15 = lane & 15;
    const int lh = lane >> 4;

    const float cv = cur[head];
    const float c_h = (cv * (float)SPANn - (float)(SPANn - 1)) * (1.0f / 32.0f) + 1.0f;

    const short* KbB = Kb + (size_t)b * NKEY * DHn;
    const short* VtB = Vt + (size_t)b * DHn * NKEY;

    // Q fragment (B operand: col = l15 -> q-row m0+16w+l15, k = 8lh+e -> d)
    s16x8 qfrag[2];
    {
        const float* qrow = q + ((size_t)b * Mn + m0 + 16 * w + l15) * DHn;
#pragma unroll
        for (int t2 = 0; t2 < 2; ++t2) {
            int d0 = 32 * t2 + 8 * lh;
#pragma unroll
            for (int e = 0; e < 8; ++e)
                qfrag[t2][e] = f2bf(qrow[d0 + e] * RSQRT_D);
        }
    }

    f32x4 o_acc[4];
#pragma unroll
    for (int c = 0; c < 4; ++c) o_acc[c] = (f32x4){0.f, 0.f, 0.f, 0.f};
    float zs = 0.f, zm = 0.f;

    // prologue: stage tile 0
    stage64x64(KbB + (size_t)m0 * DHn, DHn, &KA[0][0], tid);
    stage64x64(VtB + m0, NKEY, &VA[0][0], tid);
    stage64x64(peT, DHn, &PE[0][0], tid);
    __syncthreads();

    const int posrow = (16 * w + l15) * (POS_STR * 2);  // byte base of this lane's Pos row
    const int prow = 16 * w + l15;
    const int swp = (prow & 7) << 4;

#pragma unroll 1
    for (int t = 0; t < NITER; ++t) {
        const int D = 64 * t;
        const int cb = t & 1;

        // ---- issue next-tile staging (lands by the bottom barrier) ----
        if (t < NITER - 1) {
            const int n0n = m0 + D + 64;
            stage64x64(KbB + (size_t)n0n * DHn, DHn, &KA[cb ^ 1][0], tid);
            stage64x64(VtB + n0n, NKEY, &VA[cb ^ 1][0], tid);
            if (t + 1 < 16)
                stage64x64(peT + (size_t)(D + 64) * DHn, DHn, &PE[cb ^ 1][0], tid);
        }

        // ---- pos GEMM (swapped): rows = l-offsets, col = i (wave-private) ----
        if (t < 16) {
            const char* PEb = (const char*)&PE[cb][0];
#pragma unroll
            for (int c = 0; c < 4; ++c) {
                int ar = 16 * c + l15;
                int sw = (ar & 7) << 4;
                const char* base = PEb + ar * 128;
                s16x8 a0 = *(const s16x8*)(base + ((16 * lh) ^ sw));
                s16x8 a1 = *(const s16x8*)(base + ((64 + 16 * lh) ^ sw));
                f32x4 pa = (f32x4){0.f, 0.f, 0.f, 0.f};
                pa = __builtin_amdgcn_mfma_f32_16x16x32_bf16(a0, qfrag[0], pa, 0, 0, 0);
                pa = __builtin_amdgcn_mfma_f32_16x16x32_bf16(a1, qfrag[1], pa, 0, 0, 0);
                int ent = (D + 16 * c + 4 * lh) & 127;
                s16x4 pk;
#pragma unroll
                for (int r = 0; r < 4; ++r) pk[r] = f2bf(pa[r]);
                *(s16x4*)((char*)Pos + posrow + (ent << 1)) = pk;
            }
        }

        // ---- S^T = K Q (swapped) + pos + exp + span-mask -> P (b64 writes) ----
        {
            const char* Kbf = (const char*)&KA[cb][0];
#pragma unroll
            for (int c = 0; c < 4; ++c) {
                int ar = 16 * c + l15;
                int sw = (ar & 7) << 4;
                const char* base = Kbf + ar * 128;
                s16x8 a0 = *(const s16x8*)(base + ((16 * lh) ^ sw));
                s16x8 a1 = *(const s16x8*)(base + ((64 + 16 * lh) ^ sw));
                f32x4 sa = (f32x4){0.f, 0.f, 0.f, 0.f};
                sa = __builtin_amdgcn_mfma_f32_16x16x32_bf16(a0, qfrag[0], sa, 0, 0, 0);
                sa = __builtin_amdgcn_mfma_f32_16x16x32_bf16(a1, qfrag[1], sa, 0, 0, 0);
                int lbase = D + 16 * c + 4 * lh - 16 * w - l15;
                s16x4 pk;
#pragma unroll
                for (int r = 0; r < 4; ++r) {
                    int l = lbase + r;
                    float pos = bf2f(*(const short*)((const char*)Pos + posrow + ((l & 127) << 1)));
                    float s = sa[r] + pos;
                    float p = __expf(s);
                    p = ((unsigned)l < 1024u) ? p : 0.0f;
                    float mk = fminf(fmaxf((float)l * (1.0f / 32.0f) + c_h, 0.0f), 1.0f);
                    float pm = p * mk;
                    zs += p;
                    zm += pm;
                    pk[r] = f2bf(pm);
                }
                *(s16x4*)((char*)P + prow * 128 + ((32 * c + 8 * lh) ^ swp)) = pk;
            }
        }

        // ---- PV: O += P * V (wave-private P) ----
        {
            const char* pb = (const char*)P + prow * 128;
            s16x8 pf0 = *(const s16x8*)(pb + ((16 * lh) ^ swp));
            s16x8 pf1 = *(const s16x8*)(pb + ((64 + 16 * lh) ^ swp));
            const char* Vbf = (const char*)&VA[cb][0];
            __builtin_amdgcn_s_setprio(1);
#pragma unroll
            for (int c = 0; c < 4; ++c) {
                int vr = 16 * c + l15;
                int swv = (vr & 7) << 4;
                const char* vb = Vbf + vr * 128;
                s16x8 v0 = *(const s16x8*)(vb + ((16 * lh) ^ swv));
                s16x8 v1 = *(const s16x8*)(vb + ((64 + 16 * lh) ^ swv));
                o_acc[c] = __builtin_amdgcn_mfma_f32_16x16x32_bf16(pf0, v0, o_acc[c], 0, 0, 0);
                o_acc[c] = __builtin_amdgcn_mfma_f32_16x16x32_bf16(pf1, v1, o_acc[c], 0, 0, 0);
            }
            __builtin_amdgcn_s_setprio(0);
        }

        __syncthreads();  // drains vmcnt: next tile staged; all waves done with cur bufs
    }

    // ---- z reductions: sum over lh groups (cols already in-lane) ----
    zs += __shfl_xor(zs, 16, 64);
    zs += __shfl_xor(zs, 32, 64);
    zm += __shfl_xor(zm, 16, 64);
    zm += __shfl_xor(zm, 32, 64);

    // ---- epilogue ----
#pragma unroll
    for (int r = 0; r < 4; ++r) {
        float zmr = __shfl(zm, 4 * lh + r, 64);
        float zsr = __shfl(zs, 4 * lh + r, 64);
        float dn = 1.0f / (zmr + 1e-8f * zsr);
        float* orow = out + ((size_t)b * Mn + m0 + 16 * w + 4 * lh + r) * DHn;
#pragma unroll
        for (int c = 0; c < 4; ++c)
            orow[16 * c + l15] = o_acc[c][r] * dn;
    }
}

// ---------------- round-1 fallback (used when ws_size is too small) ----------------
#define KSTR 72
#define PSTR 136

__global__ __launch_bounds__(256, 3) void attn_kernel(
    const float* __restrict__ q, const float* __restrict__ key,
    const float* __restrict__ val, const short* __restrict__ peT,
    const float* __restrict__ cur, float* __restrict__ out) {
    __shared__ short K_lds[64][KSTR];
    __shared__ short Vt_lds[DHn][KSTR];
    __shared__ short P_lds[64][KSTR];
    __shared__ short Pos_lds[64][PSTR];

    const int b = blockIdx.x & 63;
    const int m0 = (blockIdx.x >> 6) << 6;
    const int head = b & 7;
    const int tid = threadIdx.x;
    const int lane = tid & 63;
    const int w = tid >> 6;
    const int l15 = lane & 15;
    const int lh = lane >> 4;

    const float cv = cur[head];
    const float c_h = (cv * (float)SPANn - (float)(SPANn - 1)) * (1.0f / 32.0f) + 1.0f;

    s16x8 qfrag[2];
    {
        const float* qrow = q + ((size_t)b * Mn + (m0 + 16 * w + l15)) * DHn;
#pragma unroll
        for (int t = 0; t < 2; ++t) {
            int d0 = 32 * t + 8 * lh;
#pragma unroll
            for (int e = 0; e < 8; ++e)
                qfrag[t][e] = f2bf(qrow[d0 + e] * RSQRT_D);
        }
    }

    f32x4 o_acc[4];
#pragma unroll
    for (int c = 0; c < 4; ++c) o_acc[c] = (f32x4){0.f, 0.f, 0.f, 0.f};
    float zsum[4] = {0.f, 0.f, 0.f, 0.f};
    float zmsum[4] = {0.f, 0.f, 0.f, 0.f};

    const int r_stage = tid >> 2;
    const int c_stage = (tid & 3) * 16;

#pragma unroll 1
    for (int t = 0; t < NITER; ++t) {
        const int n0 = m0 + 64 * t;
        const int D = 64 * t;
        __syncthreads();
        {
            const float* src = key + ((size_t)b * NKEY + (n0 + r_stage)) * DHn + c_stage;
            s16x8 a0, a1;
#pragma unroll
            for (int e = 0; e < 8; ++e) a0[e] = f2bf(src[e]);
#pragma unroll
            for (int e = 0; e < 8; ++e) a1[e] = f2bf(src[8 + e]);
            *(s16x8*)&K_lds[r_stage][c_stage] = a0;
            *(s16x8*)&K_lds[r_stage][c_stage + 8] = a1;
        }
        {
            const float* src = val + ((size_t)b * NKEY + (n0 + r_stage)) * DHn + c_stage;
#pragma unroll
            for (int e = 0; e < 16; ++e)
                Vt_lds[c_stage + e][r_stage] = f2bf(src[e]);
        }
        if (t < 16) {
            const int l0 = 64 * t;
#pragma unroll
            for (int c = 0; c < 4; ++c) {
                int lcol = l0 + 16 * c + l15;
                s16x8 b0 = *(const s16x8*)&peT[(size_t)lcol * DHn + 8 * lh];
                s16x8 b1 = *(const s16x8*)&peT[(size_t)lcol * DHn + 32 + 8 * lh];
                f32x4 acc = (f32x4){0.f, 0.f, 0.f, 0.f};
                acc = __builtin_amdgcn_mfma_f32_16x16x32_bf16(qfrag[0], b0, acc, 0, 0, 0);
                acc = __builtin_amdgcn_mfma_f32_16x16x32_bf16(qfrag[1], b1, acc, 0, 0, 0);
                int ent = lcol & 127;
#pragma unroll
                for (int r = 0; r < 4; ++r)
                    Pos_lds[16 * w + 4 * lh + r][ent] = f2bf(acc[r]);
            }
        }
        __syncthreads();
#pragma unroll
        for (int c = 0; c < 4; ++c) {
            s16x8 k0 = *(const s16x8*)&K_lds[16 * c + l15][8 * lh];
            s16x8 k1 = *(const s16x8*)&K_lds[16 * c + l15][32 + 8 * lh];
            f32x4 acc = (f32x4){0.f, 0.f, 0.f, 0.f};
            acc = __builtin_amdgcn_mfma_f32_16x16x32_bf16(qfrag[0], k0, acc, 0, 0, 0);
            acc = __builtin_amdgcn_mfma_f32_16x16x32_bf16(qfrag[1], k1, acc, 0, 0, 0);
#pragma unroll
            for (int r = 0; r < 4; ++r) {
                int i = 16 * w + 4 * lh + r;
                int l = D + 16 * c + l15 - (16 * w + 4 * lh + r);
                bool valid = (l >= 0) && (l < SPANn);
                float pos = bf2f(Pos_lds[i][l & 127]);
                float s = acc[r] + pos;
                float p = __expf(s);
                p = valid ? p : 0.0f;
                float mk = fminf(fmaxf((float)l * (1.0f / 32.0f) + c_h, 0.0f), 1.0f);
                float pm = p * mk;
                zsum[r] += p;
                zmsum[r] += pm;
                P_lds[i][16 * c + l15] = f2bf(pm);
            }
        }
        __syncthreads();
#pragma unroll
        for (int c = 0; c < 4; ++c) {
            s16x8 p0 = *(const s16x8*)&P_lds[16 * w + l15][8 * lh];
            s16x8 p1 = *(const s16x8*)&P_lds[16 * w + l15][32 + 8 * lh];
            s16x8 v0 = *(const s16x8*)&Vt_lds[16 * c + l15][8 * lh];
            s16x8 v1 = *(const s16x8*)&Vt_lds[16 * c + l15][32 + 8 * lh];
            o_acc[c] = __builtin_amdgcn_mfma_f32_16x16x32_bf16(p0, v0, o_acc[c], 0, 0, 0);
            o_acc[c] = __builtin_amdgcn_mfma_f32_16x16x32_bf16(p1, v1, o_acc[c], 0, 0, 0);
        }
    }

#pragma unroll
    for (int r = 0; r < 4; ++r) {
#pragma unroll
        for (int off = 1; off < 16; off <<= 1) {
            zsum[r] += __shfl_xor(zsum[r], off, 64);
            zmsum[r] += __shfl_xor(zmsum[r], off, 64);
        }
    }
#pragma unroll
    for (int r = 0; r < 4; ++r) {
        float denom = 1.0f / (zmsum[r] + 1e-8f * zsum[r]);
        int i = 16 * w + 4 * lh + r;
        float* orow = out + ((size_t)b * Mn + (m0 + i)) * DHn;
#pragma unroll
        for (int c = 0; c < 4; ++c)
            orow[16 * c + l15] = o_acc[c][r] * denom;
    }
}

extern "C" void kernel_launch(void* const* d_in, const int* in_sizes, int n_in,
                              void* d_out, int out_size, void* d_ws, size_t ws_size,
                              hipStream_t stream) {
    (void)in_sizes; (void)n_in; (void)out_size;
    const float* q = (const float*)d_in[0];
    const float* key = (const float*)d_in[1];
    const float* val = (const float*)d_in[2];
    const float* pe = (const float*)d_in[3];
    const float* cur = (const float*)d_in[4];
    float* out = (float*)d_out;

    const size_t KV_ELEMS = (size_t)BHn * NKEY * DHn;       // 8,388,608
    const size_t PET_ELEMS = (size_t)SPANn * DHn;           // 65,536
    const size_t need = (2 * KV_ELEMS + PET_ELEMS) * sizeof(short);

    if (ws_size >= need) {
        short* Kb = (short*)d_ws;
        short* Vt = Kb + KV_ELEMS;
        short* peT = Vt + KV_ELEMS;
        k_convert_kernel<<<4096, 256, 0, stream>>>(key, Kb);
        v_transpose_kernel<<<BHn * (NKEY / 64), 256, 0, stream>>>(val, Vt);
        pe_transpose_kernel<<<256, 256, 0, stream>>>(pe, peT);
        attn2_kernel<<<64 * (Mn / 64), 256, 0, stream>>>(q, Kb, Vt, peT, cur, out);
    } else {
        short* peT = (short*)d_ws;  // 128 KB
        pe_transpose_kernel<<<256, 256, 0, stream>>>(pe, peT);
        attn_kernel<<<64 * (Mn / 64), 256, 0, stream>>>(q, key, val, peT, cur, out);
    }
}